// Round 5
// baseline (537.225 us; speedup 1.0000x reference)
//
#include <hip/hip_runtime.h>

#define TT 65
#define DD 32
#define HH 128
#define NSTEP 64

typedef __attribute__((ext_vector_type(8))) short bf16x8;
typedef __attribute__((ext_vector_type(4))) short bf16x4;
typedef __attribute__((ext_vector_type(4))) float f32x4;
typedef __attribute__((ext_vector_type(4))) unsigned int u32x4;
typedef __attribute__((ext_vector_type(2))) unsigned int u32x2;

// 16x16x16 bf16 MFMA builtin (name varies across ROCm versions)
#if __has_builtin(__builtin_amdgcn_mfma_f32_16x16x16bf16_1k)
#define MFMA16(A,B,C) __builtin_amdgcn_mfma_f32_16x16x16bf16_1k((A),(B),(C),0,0,0)
#elif __has_builtin(__builtin_amdgcn_mfma_f32_16x16x16_bf16)
#define MFMA16(A,B,C) __builtin_amdgcn_mfma_f32_16x16x16_bf16((A),(B),(C),0,0,0)
#else
static __device__ __forceinline__ f32x4 mfma16_asm(bf16x4 a, bf16x4 b, f32x4 c) {
    f32x4 d;
    asm("v_mfma_f32_16x16x16_bf16 %0, %1, %2, %3" : "=v"(d) : "v"(a), "v"(b), "v"(c));
    return d;
}
#define MFMA16(A,B,C) mfma16_asm((A),(B),(C))
#endif

__device__ constexpr float ATc[6][5] = {
    {0.f, 0.f, 0.f, 0.f, 0.f},
    {0.2f, 0.f, 0.f, 0.f, 0.f},
    {3.f/40.f, 9.f/40.f, 0.f, 0.f, 0.f},
    {44.f/45.f, -56.f/15.f, 32.f/9.f, 0.f, 0.f},
    {19372.f/6561.f, -25360.f/2187.f, 64448.f/6561.f, -212.f/729.f, 0.f},
    {9017.f/3168.f, -355.f/33.f, 46732.f/5247.f, 49.f/176.f, -5103.f/18656.f}
};
__device__ constexpr float BTc[6] = {35.f/384.f, 0.f, 500.f/1113.f, 125.f/192.f,
                                     -2187.f/6784.f, 11.f/84.f};

struct Frag3  { bf16x8 h, m, l; };
struct Frag3s { bf16x4 h, m, l; };

__device__ __forceinline__ float tanh_fast(float x) {
    float e = __expf(2.0f * x);
    return fmaf(-2.0f, __builtin_amdgcn_rcpf(e + 1.0f), 1.0f);
}

// 3-term bf16 truncation split: v = h + m + l + O(2^-24 |v|), exact residuals.
__device__ __forceinline__ Frag3 split8(const float* v) {
    unsigned int wh[4], wm[4], wl[4];
    #pragma unroll
    for (int p = 0; p < 4; ++p) {
        float a = v[2*p], b = v[2*p+1];
        unsigned int ua = __float_as_uint(a), ub = __float_as_uint(b);
        unsigned int uam = ua & 0xFFFF0000u, ubm = ub & 0xFFFF0000u;
        wh[p] = ubm | (ua >> 16);
        float ra = a - __uint_as_float(uam);
        float rb = b - __uint_as_float(ubm);
        unsigned int ura = __float_as_uint(ra), urb = __float_as_uint(rb);
        unsigned int uram = ura & 0xFFFF0000u, urbm = urb & 0xFFFF0000u;
        wm[p] = urbm | (ura >> 16);
        float sa = ra - __uint_as_float(uram);
        float sb = rb - __uint_as_float(urbm);
        wl[p] = (__float_as_uint(sb) & 0xFFFF0000u) | (__float_as_uint(sa) >> 16);
    }
    Frag3 f;
    u32x4 H = {wh[0], wh[1], wh[2], wh[3]};
    u32x4 M = {wm[0], wm[1], wm[2], wm[3]};
    u32x4 L = {wl[0], wl[1], wl[2], wl[3]};
    f.h = __builtin_bit_cast(bf16x8, H);
    f.m = __builtin_bit_cast(bf16x8, M);
    f.l = __builtin_bit_cast(bf16x8, L);
    return f;
}

__device__ __forceinline__ Frag3s split4(f32x4 v) {
    unsigned int wh[2], wm[2], wl[2];
    #pragma unroll
    for (int p = 0; p < 2; ++p) {
        float a = v[2*p], b = v[2*p+1];
        unsigned int ua = __float_as_uint(a), ub = __float_as_uint(b);
        unsigned int uam = ua & 0xFFFF0000u, ubm = ub & 0xFFFF0000u;
        wh[p] = ubm | (ua >> 16);
        float ra = a - __uint_as_float(uam);
        float rb = b - __uint_as_float(ubm);
        unsigned int ura = __float_as_uint(ra), urb = __float_as_uint(rb);
        unsigned int uram = ura & 0xFFFF0000u, urbm = urb & 0xFFFF0000u;
        wm[p] = urbm | (ura >> 16);
        float sa = ra - __uint_as_float(uram);
        float sb = rb - __uint_as_float(urbm);
        wl[p] = (__float_as_uint(sb) & 0xFFFF0000u) | (__float_as_uint(sa) >> 16);
    }
    Frag3s f;
    u32x2 H = {wh[0], wh[1]};
    u32x2 M = {wm[0], wm[1]};
    u32x2 L = {wl[0], wl[1]};
    f.h = __builtin_bit_cast(bf16x4, H);
    f.m = __builtin_bit_cast(bf16x4, M);
    f.l = __builtin_bit_cast(bf16x4, L);
    return f;
}

// 6-product split accumulate (keeps terms through 2^-16; error ~2^-24)
__device__ __forceinline__ f32x4 mac3(const Frag3& A, const Frag3& B, f32x4 acc) {
    acc = __builtin_amdgcn_mfma_f32_16x16x32_bf16(A.h, B.h, acc, 0, 0, 0);
    acc = __builtin_amdgcn_mfma_f32_16x16x32_bf16(A.h, B.m, acc, 0, 0, 0);
    acc = __builtin_amdgcn_mfma_f32_16x16x32_bf16(A.m, B.h, acc, 0, 0, 0);
    acc = __builtin_amdgcn_mfma_f32_16x16x32_bf16(A.h, B.l, acc, 0, 0, 0);
    acc = __builtin_amdgcn_mfma_f32_16x16x32_bf16(A.m, B.m, acc, 0, 0, 0);
    acc = __builtin_amdgcn_mfma_f32_16x16x32_bf16(A.l, B.h, acc, 0, 0, 0);
    return acc;
}
__device__ __forceinline__ f32x4 mac3s(const Frag3s& A, const Frag3s& B, f32x4 acc) {
    acc = MFMA16(A.h, B.h, acc);
    acc = MFMA16(A.h, B.m, acc);
    acc = MFMA16(A.m, B.h, acc);
    acc = MFMA16(A.h, B.l, acc);
    acc = MFMA16(A.m, B.m, acc);
    acc = MFMA16(A.l, B.h, acc);
    return acc;
}

// Block = 8 waves = 512 thr = 16 ODE rows. Per stage, wave w:
//   m1 tile w: z[c] for c in [16w,16w+16) via 16x16x32 (6 MFMA), tanh, split4.
//   m2: D-frag of m1 (4q+e, r) == B-frag of 16x16x16 (4q+j, r): z feeds m2
//   IN REGISTERS (no LDS bounce). Both d-tiles over K=16 slice -> partial -> pb.
//   barrier; lane (w,q,r) owns state (d=4w+q, row r): reduce 8 partials
//   (imm-offset ds_read_b32), update y/k, write next stage arg; barrier.
// All LDS arrays are [16 rows][32 f32] with idx^((r&7)<<2) swizzle (R4-proven).
__global__ __launch_bounds__(512, 4)
void NeuralODE_dopri5_w8(const float* __restrict__ x, const float* __restrict__ t,
                         const float* __restrict__ W1, const float* __restrict__ b1,
                         const float* __restrict__ W2, const float* __restrict__ b2,
                         float* __restrict__ out)
{
    __shared__ __align__(16) float ytb[16 * 32];        // stage argument
    __shared__ __align__(16) float pb [8][16 * 32];     // m2 partials per wave

    const int tid = threadIdx.x;
    const int w   = tid >> 6;
    const int l   = tid & 63;
    const int r   = l & 15;          // lane-low: M-index for A-loads, N (row) for B/D
    const int q   = l >> 4;
    const int swz = (r & 7) << 2;
    const int row = blockIdx.x * 16 + r;
    const int d_own = 4 * w + q;     // owned state dimension (bijective over 8w x 4q)

    // ---- static weight fragments ----
    Frag3 W1f; f32x4 b1f;
    {
        float v[8];
        *(f32x4*)&v[0] = *(const f32x4*)&W1[(16*w + r) * DD + 8*q];
        *(f32x4*)&v[4] = *(const f32x4*)&W1[(16*w + r) * DD + 8*q + 4];
        W1f = split8(v);
        b1f = *(const f32x4*)&b1[16*w + 4*q];
    }
    Frag3s W2f[2];
    #pragma unroll
    for (int tt = 0; tt < 2; ++tt) {
        f32x4 v = *(const f32x4*)&W2[(16*tt + r) * HH + 16*w + 4*q];
        W2f[tt] = split4(v);
    }
    const float b2e = b2[d_own];

    // ---- loop-invariant LDS addresses ----
    float* const yt_w = &ytb[r * 32 + (d_own ^ swz)];            // owner write/ read slot
    const float* const b1r0 = &ytb[r * 32 + ((8*q)     ^ swz)];  // B1 low half
    const float* const b1r1 = &ytb[r * 32 + ((8*q + 4) ^ swz)];  // B1 high half
    float* const pbw0 = &pb[w][r * 32 + ((     4*q) ^ swz)];
    float* const pbw1 = &pb[w][r * 32 + ((16 + 4*q) ^ swz)];
    const float* const pred = &pb[0][r * 32 + (d_own ^ swz)];    // reduce base (+512*v)

    // ---- state init: y0 -> ytb, out step 0 ----
    float y = x[(size_t)row * (TT*DD) + d_own];
    *yt_w = y;
    out[(size_t)row * (TT*DD) + d_own] = y;
    float kx[5];
    #pragma unroll
    for (int j = 0; j < 5; ++j) kx[j] = 0.f;
    __syncthreads();

    #pragma unroll 1
    for (int step = 0; step < NSTEP; ++step) {
        const float h = t[step + 1] - t[step];
        float bacc = 0.f;

        #pragma unroll
        for (int s = 0; s < 6; ++s) {
            // ---- B1 fragment (full yt row r) ----
            float vb[8];
            *(f32x4*)&vb[0] = *(const f32x4*)b1r0;
            *(f32x4*)&vb[4] = *(const f32x4*)b1r1;
            Frag3 B1 = split8(vb);

            // ---- m1 tile w + tanh + split (z stays in registers) ----
            f32x4 z = mac3(W1f, B1, b1f);
            #pragma unroll
            for (int e = 0; e < 4; ++e) z[e] = tanh_fast(z[e]);
            Frag3s Z = split4(z);

            // ---- m2: both d-tiles over own K=16 slice (layout identity) ----
            const f32x4 zero = {0.f, 0.f, 0.f, 0.f};
            f32x4 p0 = mac3s(W2f[0], Z, zero);
            f32x4 p1 = mac3s(W2f[1], Z, zero);
            *(f32x4*)pbw0 = p0;
            *(f32x4*)pbw1 = p1;
            __syncthreads();

            // ---- reduce 8 partials for owned (d_own, r) ----
            float pv[8];
            #pragma unroll
            for (int v8 = 0; v8 < 8; ++v8) pv[v8] = pred[v8 * 512];
            float kd = b2e + (((pv[0] + pv[1]) + (pv[2] + pv[3]))
                            + ((pv[4] + pv[5]) + (pv[6] + pv[7])));
            if (s < 5) kx[s] = kd;
            bacc = fmaf(BTc[s], kd, bacc);

            if (s < 5) {
                // next stage argument: yt = y + h * sum_{j<=s} A[s+1][j] k_j
                float at = ATc[s+1][s] * kd;
                #pragma unroll
                for (int j = 0; j < 5; ++j)
                    if (j < s) at = fmaf(ATc[s+1][j], kx[j], at);
                *yt_w = fmaf(h, at, y);
            } else {
                y = fmaf(h, bacc, y);
                *yt_w = y;   // stage-0 argument of next step
                out[(size_t)row * (TT*DD) + (size_t)(step+1) * DD + d_own] = y;
            }
            __syncthreads();
        }
    }
}

extern "C" void kernel_launch(void* const* d_in, const int* in_sizes, int n_in,
                              void* d_out, int out_size, void* d_ws, size_t ws_size,
                              hipStream_t stream) {
    (void)in_sizes; (void)n_in; (void)d_ws; (void)ws_size; (void)out_size;
    const float* x  = (const float*)d_in[0];
    const float* t  = (const float*)d_in[1];
    // d_in[2] = itv, d_in[3] = itv_mask : unused by the reference math
    const float* W1 = (const float*)d_in[4];
    const float* b1 = (const float*)d_in[5];
    const float* W2 = (const float*)d_in[6];
    const float* b2 = (const float*)d_in[7];
    float* out = (float*)d_out;

    dim3 grid(8192 / 16);   // 512 blocks x 8 waves = 4096 waves (16/CU, 4/SIMD)
    dim3 block(512);
    hipLaunchKernelGGL(NeuralODE_dopri5_w8, grid, block, 0, stream,
                       x, t, W1, b1, W2, b2, out);
}

// Round 6
// 439.035 us; speedup vs baseline: 1.2236x; 1.2236x over previous
//
#include <hip/hip_runtime.h>

#define TT 65
#define DD 32
#define HH 128
#define NSTEP 64

typedef __attribute__((ext_vector_type(8))) short bf16x8;
typedef __attribute__((ext_vector_type(4))) float f32x4;
typedef __attribute__((ext_vector_type(4))) unsigned int u32x4;

__device__ constexpr float ATc[6][5] = {
    {0.f, 0.f, 0.f, 0.f, 0.f},
    {0.2f, 0.f, 0.f, 0.f, 0.f},
    {3.f/40.f, 9.f/40.f, 0.f, 0.f, 0.f},
    {44.f/45.f, -56.f/15.f, 32.f/9.f, 0.f, 0.f},
    {19372.f/6561.f, -25360.f/2187.f, 64448.f/6561.f, -212.f/729.f, 0.f},
    {9017.f/3168.f, -355.f/33.f, 46732.f/5247.f, 49.f/176.f, -5103.f/18656.f}
};
__device__ constexpr float BTc[6] = {35.f/384.f, 0.f, 500.f/1113.f, 125.f/192.f,
                                     -2187.f/6784.f, 11.f/84.f};

struct Frag3 { bf16x8 h, m, l; };

__device__ __forceinline__ float tanh_fast(float x) {
    float e = __expf(2.0f * x);
    return fmaf(-2.0f, __builtin_amdgcn_rcpf(e + 1.0f), 1.0f);
}

// 3-term bf16 truncation split: v = h + m + l + O(2^-24 |v|), exact residuals.
__device__ __forceinline__ Frag3 split8(const float* v) {
    unsigned int wh[4], wm[4], wl[4];
    #pragma unroll
    for (int p = 0; p < 4; ++p) {
        float a = v[2*p], b = v[2*p+1];
        unsigned int ua = __float_as_uint(a), ub = __float_as_uint(b);
        unsigned int uam = ua & 0xFFFF0000u, ubm = ub & 0xFFFF0000u;
        wh[p] = ubm | (ua >> 16);
        float ra = a - __uint_as_float(uam);
        float rb = b - __uint_as_float(ubm);
        unsigned int ura = __float_as_uint(ra), urb = __float_as_uint(rb);
        unsigned int uram = ura & 0xFFFF0000u, urbm = urb & 0xFFFF0000u;
        wm[p] = urbm | (ura >> 16);
        float sa = ra - __uint_as_float(uram);
        float sb = rb - __uint_as_float(urbm);
        wl[p] = (__float_as_uint(sb) & 0xFFFF0000u) | (__float_as_uint(sa) >> 16);
    }
    Frag3 f;
    u32x4 H = {wh[0], wh[1], wh[2], wh[3]};
    u32x4 M = {wm[0], wm[1], wm[2], wm[3]};
    u32x4 L = {wl[0], wl[1], wl[2], wl[3]};
    f.h = __builtin_bit_cast(bf16x8, H);
    f.m = __builtin_bit_cast(bf16x8, M);
    f.l = __builtin_bit_cast(bf16x8, L);
    return f;
}

// Split 2 scalars into 3 packed bf16-pair words (lo half = a, hi half = b).
__device__ __forceinline__ void split2pack(float a, float b,
                                           unsigned int& ph, unsigned int& pm,
                                           unsigned int& pl) {
    unsigned int ua = __float_as_uint(a), ub = __float_as_uint(b);
    unsigned int ham = ua & 0xFFFF0000u, hbm = ub & 0xFFFF0000u;
    ph = (ua >> 16) | hbm;
    float ra = a - __uint_as_float(ham);
    float rb = b - __uint_as_float(hbm);
    unsigned int ura = __float_as_uint(ra), urb = __float_as_uint(rb);
    unsigned int ram = ura & 0xFFFF0000u, rbm = urb & 0xFFFF0000u;
    pm = (ura >> 16) | rbm;
    float sa = ra - __uint_as_float(ram);
    float sb = rb - __uint_as_float(rbm);
    pl = (__float_as_uint(sa) >> 16) | (__float_as_uint(sb) & 0xFFFF0000u);
}

// 6-product split accumulate, 2 independent chains of 3 (shorter dep chain).
__device__ __forceinline__ f32x4 mac3b(const Frag3& A, const Frag3& B, f32x4 cinit) {
    f32x4 a0 = cinit;
    f32x4 a1 = {0.f, 0.f, 0.f, 0.f};
    a0 = __builtin_amdgcn_mfma_f32_16x16x32_bf16(A.h, B.h, a0, 0, 0, 0);
    a1 = __builtin_amdgcn_mfma_f32_16x16x32_bf16(A.h, B.m, a1, 0, 0, 0);
    a0 = __builtin_amdgcn_mfma_f32_16x16x32_bf16(A.m, B.h, a0, 0, 0, 0);
    a1 = __builtin_amdgcn_mfma_f32_16x16x32_bf16(A.m, B.m, a1, 0, 0, 0);
    a0 = __builtin_amdgcn_mfma_f32_16x16x32_bf16(A.l, B.h, a0, 0, 0, 0);
    a1 = __builtin_amdgcn_mfma_f32_16x16x32_bf16(A.h, B.l, a1, 0, 0, 0);
    #pragma unroll
    for (int i = 0; i < 4; ++i) a0[i] += a1[i];
    return a0;
}

// Block = 4 waves = 16 ODE rows (R4 structure). Changes vs R4:
//   yt is stored as 3 bf16 planes (h/m/l), split ONCE by owner lanes ->
//   consumers ds_read_b128 a ready B1 fragment (no per-wave split8 of yt).
//   Plane swizzle: u32 block' = block ^ ((r>>1)&3): writes 2-way, reads 2-way.
//   mac3 uses 2 accumulator chains; h comes from a lane-shuffle.
__global__ __launch_bounds__(256, 2)
void NeuralODE_dopri5_r6(const float* __restrict__ x, const float* __restrict__ t,
                         const float* __restrict__ W1, const float* __restrict__ b1,
                         const float* __restrict__ W2, const float* __restrict__ b2,
                         float* __restrict__ out)
{
    __shared__ unsigned int ytp[3][16][16];      // yt planes: [plane][row][16 u32]
    __shared__ __align__(16) float zb[4][16 * 32];   // per-wave z bounce (f32)
    __shared__ __align__(16) float pb[4][16 * 32];   // m2 partials per wave

    const int tid = threadIdx.x;
    const int w   = tid >> 6;
    const int l   = tid & 63;
    const int r   = l & 15;
    const int q   = l >> 4;
    const int g   = (r >> 1) & 3;                // plane block swizzle
    const int swz = (r & 7) << 2;                // f32-block swizzle (R4-proven)
    const int row = blockIdx.x * 16 + r;
    const int d0  = 8 * w + 2 * q;               // owned state pair

    // ---- static weight fragments ----
    Frag3 W1f[2], W2f[2];
    f32x4 b1f[2];
    {
        float v[8];
        #pragma unroll
        for (int i = 0; i < 2; ++i) {
            int m = 2 * w + i;
            *(f32x4*)&v[0] = *(const f32x4*)&W1[(16*m + r) * DD + 8*q];
            *(f32x4*)&v[4] = *(const f32x4*)&W1[(16*m + r) * DD + 8*q + 4];
            W1f[i] = split8(v);
            b1f[i] = *(const f32x4*)&b1[16*m + 4*q];
        }
        #pragma unroll
        for (int m2 = 0; m2 < 2; ++m2) {
            *(f32x4*)&v[0] = *(const f32x4*)&W2[(16*m2 + r) * HH + 32*w + 8*q];
            *(f32x4*)&v[4] = *(const f32x4*)&W2[(16*m2 + r) * HH + 32*w + 8*q + 4];
            W2f[m2] = split8(v);
        }
    }
    const float b2x = b2[d0], b2y = b2[d0 + 1];

    // ---- loop-invariant LDS addresses ----
    // owner writes its packed pair at logical u32 idx 4w+q -> physical (w^g)*4+q
    unsigned int* const ytw0 = &ytp[0][r][((w ^ g) << 2) + q];
    unsigned int* const ytw1 = &ytp[1][r][((w ^ g) << 2) + q];
    unsigned int* const ytw2 = &ytp[2][r][((w ^ g) << 2) + q];
    // reader: logical block q -> physical block q^g
    const u32x4* const ytr0 = (const u32x4*)&ytp[0][r][(q ^ g) << 2];
    const u32x4* const ytr1 = (const u32x4*)&ytp[1][r][(q ^ g) << 2];
    const u32x4* const ytr2 = (const u32x4*)&ytp[2][r][(q ^ g) << 2];
    float* const zbw0 = &zb[w][r * 32 + (((16*0) + 4*q) ^ swz)];
    float* const zbw1 = &zb[w][r * 32 + (((16*1) + 4*q) ^ swz)];
    const float* const zbr0 = &zb[w][r * 32 + ((8*q)     ^ swz)];
    const float* const zbr1 = &zb[w][r * 32 + ((8*q + 4) ^ swz)];
    float* const pbw0 = &pb[w][r * 32 + ((     4*q) ^ swz)];
    float* const pbw1 = &pb[w][r * 32 + ((16 + 4*q) ^ swz)];
    const float* const pred = &pb[0][r * 32 + (d0 ^ swz)];   // + 512*v

    // ---- h via lane shuffle (t row 0 is uniform) ----
    const float h_all = t[l + 1] - t[l];

    // ---- state init ----
    float2 y0 = *(const float2*)&x[(size_t)row * (TT*DD) + d0];
    float yx = y0.x, yy = y0.y;
    {
        unsigned int ph, pm, pl;
        split2pack(yx, yy, ph, pm, pl);
        *ytw0 = ph; *ytw1 = pm; *ytw2 = pl;
        *(float2*)&out[(size_t)row * (TT*DD) + d0] = y0;
    }
    float kxs[5], kys[5];
    __syncthreads();

    #pragma unroll 1
    for (int step = 0; step < NSTEP; ++step) {
        const float h = __shfl(h_all, step);
        float bax = 0.f, bay = 0.f;

        #pragma unroll
        for (int s = 0; s < 6; ++s) {
            // ---- B1 fragment: direct from planes (no split) ----
            Frag3 B1;
            B1.h = __builtin_bit_cast(bf16x8, *ytr0);
            B1.m = __builtin_bit_cast(bf16x8, *ytr1);
            B1.l = __builtin_bit_cast(bf16x8, *ytr2);

            // ---- m1: 2 tiles + tanh ----
            f32x4 z0 = mac3b(W1f[0], B1, b1f[0]);
            f32x4 z1 = mac3b(W1f[1], B1, b1f[1]);
            #pragma unroll
            for (int e = 0; e < 4; ++e) { z0[e] = tanh_fast(z0[e]); z1[e] = tanh_fast(z1[e]); }

            // ---- z bounce D->B (wave-private) + split ----
            *(f32x4*)zbw0 = z0;
            *(f32x4*)zbw1 = z1;
            float vz[8];
            *(f32x4*)&vz[0] = *(const f32x4*)zbr0;
            *(f32x4*)&vz[4] = *(const f32x4*)zbr1;
            Frag3 B2 = split8(vz);

            // ---- m2 partial over K-slice [32w,32w+32), both d-tiles ----
            const f32x4 zero = {0.f, 0.f, 0.f, 0.f};
            f32x4 p0 = mac3b(W2f[0], B2, zero);
            f32x4 p1 = mac3b(W2f[1], B2, zero);
            *(f32x4*)pbw0 = p0;
            *(f32x4*)pbw1 = p1;
            __syncthreads();

            // ---- owner: reduce 4 partials, update, publish next yt planes ----
            float kx = b2x, ky = b2y;
            #pragma unroll
            for (int v4 = 0; v4 < 4; ++v4) {
                float2 pp = *(const float2*)&pred[v4 * 512];
                kx += pp.x; ky += pp.y;
            }
            if (s < 5) { kxs[s] = kx; kys[s] = ky; }
            bax = fmaf(BTc[s], kx, bax);
            bay = fmaf(BTc[s], ky, bay);

            float ytx, yty;
            if (s < 5) {
                float ax = ATc[s+1][s] * kx;
                float ay = ATc[s+1][s] * ky;
                #pragma unroll
                for (int j = 0; j < 5; ++j)
                    if (j < s) { ax = fmaf(ATc[s+1][j], kxs[j], ax);
                                 ay = fmaf(ATc[s+1][j], kys[j], ay); }
                ytx = fmaf(h, ax, yx);
                yty = fmaf(h, ay, yy);
            } else {
                yx = fmaf(h, bax, yx);
                yy = fmaf(h, bay, yy);
                ytx = yx; yty = yy;
                float2 yn = {yx, yy};
                *(float2*)&out[(size_t)row * (TT*DD) + (size_t)(step+1) * DD + d0] = yn;
            }
            unsigned int ph, pm, pl;
            split2pack(ytx, yty, ph, pm, pl);
            *ytw0 = ph; *ytw1 = pm; *ytw2 = pl;
            __syncthreads();
        }
    }
}

extern "C" void kernel_launch(void* const* d_in, const int* in_sizes, int n_in,
                              void* d_out, int out_size, void* d_ws, size_t ws_size,
                              hipStream_t stream) {
    (void)in_sizes; (void)n_in; (void)d_ws; (void)ws_size; (void)out_size;
    const float* x  = (const float*)d_in[0];
    const float* t  = (const float*)d_in[1];
    // d_in[2] = itv, d_in[3] = itv_mask : unused by the reference math
    const float* W1 = (const float*)d_in[4];
    const float* b1 = (const float*)d_in[5];
    const float* W2 = (const float*)d_in[6];
    const float* b2 = (const float*)d_in[7];
    float* out = (float*)d_out;

    dim3 grid(8192 / 16);   // 512 blocks x 4 waves (R4 structure)
    dim3 block(256);
    hipLaunchKernelGGL(NeuralODE_dopri5_r6, grid, block, 0, stream,
                       x, t, W1, b1, W2, b2, out);
}